// Round 3
// baseline (1541.396 us; speedup 1.0000x reference)
//
#include <hip/hip_runtime.h>

#define N_NODES 50000
#define N_EDGES 800000
#define IN_DIM  512
#define HID     256
#define LAT     128
#define K_ITERS 10
#define BN_EPS  1e-5f

typedef __attribute__((ext_vector_type(8))) short bf16x8;
typedef __attribute__((ext_vector_type(4))) float f32x4;

// ---------------- bf16 helpers ----------------
__device__ inline float2 bf2f2(unsigned v)
{
    float lo = __builtin_bit_cast(float, v << 16);
    float hi = __builtin_bit_cast(float, v & 0xffff0000u);
    return make_float2(lo, hi);
}
__device__ inline unsigned f2bf_bits(float f)
{
    unsigned u = __builtin_bit_cast(unsigned, f);
    return (u + 0x7fffu + ((u >> 16) & 1u)) >> 16;   // RTNE
}
__device__ inline unsigned packbf(float x, float y)
{
    return f2bf_bits(x) | (f2bf_bits(y) << 16);
}

// ---------------- edge dtype detect / normalize ----------------
__global__ void detect_dtype_kernel(const int* __restrict__ ei32, int* __restrict__ flag)
{
    __shared__ int any;
    if (threadIdx.x == 0) any = 0;
    __syncthreads();
    int local = 0;
    for (int i = threadIdx.x; i < 4096; i += blockDim.x)
        local |= ei32[2 * i + 1];
    if (local) atomicOr(&any, 1);
    __syncthreads();
    if (threadIdx.x == 0) flag[0] = (any != 0) ? 1 : 0;   // 1 => data is int32
}

__global__ void convert_edges_kernel(const void* __restrict__ ei, const int* __restrict__ flag,
                                     int* __restrict__ srcE, int* __restrict__ dstE, int E)
{
    int e = blockIdx.x * blockDim.x + threadIdx.x;
    if (e >= E) return;
    if (*flag) {
        const int* p = (const int*)ei;
        srcE[e] = p[e];
        dstE[e] = p[E + e];
    } else {
        const long long* p = (const long long*)ei;
        srcE[e] = (int)p[e];
        dstE[e] = (int)p[E + e];
    }
}

// ---------------- CSR build ----------------
__global__ void init_cnt_kernel(int* __restrict__ cnt, int n)
{
    int i = blockIdx.x * blockDim.x + threadIdx.x;
    if (i < n) cnt[i] = 1;   // self-loop
}

__global__ void count_edges_kernel(const int* __restrict__ dstE, int* __restrict__ cnt, int E)
{
    int e = blockIdx.x * blockDim.x + threadIdx.x;
    if (e < E) atomicAdd(&cnt[dstE[e]], 1);
}

__global__ __launch_bounds__(1024) void scan_kernel(const int* __restrict__ cnt,
                                                    int* __restrict__ rowoff,
                                                    int* __restrict__ cursor,
                                                    float* __restrict__ dinv, int n)
{
    __shared__ int s[1024];
    const int t = threadIdx.x;
    const int chunk = (n + 1023) / 1024;
    const int lo = t * chunk;
    const int hi = min(lo + chunk, n);
    int sum = 0;
    for (int i = lo; i < hi; ++i) sum += cnt[i];
    s[t] = sum;
    __syncthreads();
    for (int off = 1; off < 1024; off <<= 1) {
        int v = (t >= off) ? s[t - off] : 0;
        __syncthreads();
        s[t] += v;
        __syncthreads();
    }
    int run = s[t] - sum;   // exclusive prefix
    for (int i = lo; i < hi; ++i) {
        rowoff[i] = run;
        cursor[i] = run;
        run += cnt[i];
        dinv[i] = rsqrtf((float)cnt[i]);
    }
    if (t == 1023) rowoff[n] = s[1023];
}

__global__ void scatter_kernel(const int* __restrict__ srcE, const int* __restrict__ dstE,
                               const float* __restrict__ dinv, int* __restrict__ cursor,
                               uint2* __restrict__ csr, int E, int n)
{
    int e = blockIdx.x * blockDim.x + threadIdx.x;
    if (e >= E + n) return;
    int s, d;
    if (e < E) { s = srcE[e]; d = dstE[e]; }
    else       { s = e - E;   d = s; }
    int pos = atomicAdd(&cursor[d], 1);
    float w = dinv[s] * dinv[d];
    csr[pos] = make_uint2((unsigned)s, __builtin_bit_cast(unsigned, w));
}

// ---------------- transpose-convert: in[R][C] f32 -> out[C][R] bf16 ----------
__global__ void transpose_cvt_kernel(const float* __restrict__ in, unsigned short* __restrict__ out,
                                     int R, int C)
{
    int idx = blockIdx.x * 256 + threadIdx.x;
    if (idx >= R * C) return;
    int c = idx / R, r = idx - c * R;
    out[idx] = (unsigned short)f2bf_bits(in[r * C + c]);
}

// ---------------- MFMA bf16 GEMM, no-LDS, B transposed [Nc][K] --------------
// Block: 256 thr = 4 waves, each wave 16 rows x 128 cols. Grid (Nc/128, ceil(M/64)).
// A: AF32 ? f32 row-major (cvt in-kernel) : bf16 row-major. Out: bf16.
// EPI 0: plain. EPI 1: relu(bn(acc + bias)).
template<int KDIM, int EPI, bool AF32>
__global__ __launch_bounds__(256) void gemm_mfma(const void* __restrict__ Ain,
                                                 const unsigned short* __restrict__ Bt,
                                                 unsigned short* __restrict__ Cout,
                                                 int M, int Nc,
                                                 const float* __restrict__ cb,
                                                 const float* __restrict__ cg,
                                                 const float* __restrict__ cbe,
                                                 const float* __restrict__ cm,
                                                 const float* __restrict__ cv)
{
    const int wave = threadIdx.x >> 6;
    const int lane = threadIdx.x & 63;
    const int s  = lane & 15;       // A-row within strip / B-col within tile / C-col
    const int kc = lane >> 4;       // k-chunk (8 elems each)
    const int wrow0   = blockIdx.y * 64 + wave * 16;
    const int colbase = blockIdx.x * 128;

    f32x4 acc[8] = {};

    const int arow = wrow0 + s;
    const bool aok = arow < M;

#pragma unroll 2
    for (int k0 = 0; k0 < KDIM; k0 += 32) {
        bf16x8 af = {};
        if (AF32) {
            if (aok) {
                const float* Ar = (const float*)Ain + (size_t)arow * KDIM + k0 + 8 * kc;
                float4 u0 = *(const float4*)Ar;
                float4 u1 = *(const float4*)(Ar + 4);
                af[0] = (short)f2bf_bits(u0.x); af[1] = (short)f2bf_bits(u0.y);
                af[2] = (short)f2bf_bits(u0.z); af[3] = (short)f2bf_bits(u0.w);
                af[4] = (short)f2bf_bits(u1.x); af[5] = (short)f2bf_bits(u1.y);
                af[6] = (short)f2bf_bits(u1.z); af[7] = (short)f2bf_bits(u1.w);
            }
        } else {
            if (aok)
                af = *(const bf16x8*)&((const unsigned short*)Ain)[(size_t)arow * KDIM + k0 + 8 * kc];
        }
#pragma unroll
        for (int t = 0; t < 8; ++t) {
            const int bn = colbase + t * 16 + s;
            bf16x8 bf = *(const bf16x8*)&Bt[(size_t)bn * KDIM + k0 + 8 * kc];
            acc[t] = __builtin_amdgcn_mfma_f32_16x16x32_bf16(af, bf, acc[t], 0, 0, 0);
        }
    }

#pragma unroll
    for (int t = 0; t < 8; ++t) {
        const int col = colbase + t * 16 + s;
        float sc = 1.f, sh = 0.f;
        if (EPI == 1) {
            sc = cg[col] * rsqrtf(cv[col] + BN_EPS);
            sh = (cb[col] - cm[col]) * sc + cbe[col];
        }
#pragma unroll
        for (int j = 0; j < 4; ++j) {
            const int crow = wrow0 + kc * 4 + j;
            if (crow < M) {
                float xv = acc[t][j];
                if (EPI == 1) xv = fmaxf(fmaf(xv, sc, sh), 0.f);
                Cout[(size_t)crow * Nc + col] = (unsigned short)f2bf_bits(xv);
            }
        }
    }
}

// ---------------- quartered XCD-affine propagate ----------------------------
// Grid 50000 blocks: quarter q = (b%8)>>1 (XCD-pair affinity), 4 nodes/block,
// 1 wave/node: 4 edge-groups x 16 lanes; lane covers dims (q*32+2s, +1).
// MODE 0: out bf16. MODE 1: bn+relu -> bf16. MODE 2: 0.9a+0.1h2 -> bf16.
// MODE 3: final: f32 z quarter to outf, bf16 mirror to outh (aliases z0h).
template<int MODE>
__global__ __launch_bounds__(256) void prop_q(const unsigned* __restrict__ in,
                                              const int* __restrict__ rowoff,
                                              const uint2* __restrict__ csr,
                                              const unsigned* __restrict__ h2h,
                                              const unsigned* __restrict__ z0h,
                                              float* __restrict__ outf,
                                              unsigned* __restrict__ outh,
                                              const float* __restrict__ bb,
                                              const float* __restrict__ bg,
                                              const float* __restrict__ bbe,
                                              const float* __restrict__ bm,
                                              const float* __restrict__ bv)
{
    const int b = blockIdx.x;
    const int q = (b & 7) >> 1;
    const int blk = ((b >> 3) << 1) | (b & 1);          // 0..12499
    const int wave = threadIdx.x >> 6;
    const int node = blk * 4 + wave;
    const int lane = threadIdx.x & 63;
    const int g = lane >> 4, s = lane & 15;
    const int e0 = rowoff[node], e1 = rowoff[node + 1];
    const int qd = q * 16 + s;                          // dword offset within row

    float ax = 0.f, ay = 0.f;
    int e = e0 + g;
    for (; e + 4 < e1; e += 8) {
        uint2 p0 = csr[e];
        uint2 p1 = csr[e + 4];
        unsigned v0 = in[(size_t)p0.x * 64 + qd];
        unsigned v1 = in[(size_t)p1.x * 64 + qd];
        float w0 = __builtin_bit_cast(float, p0.y);
        float w1 = __builtin_bit_cast(float, p1.y);
        float2 f0 = bf2f2(v0), f1 = bf2f2(v1);
        ax = fmaf(w0, f0.x, ax); ay = fmaf(w0, f0.y, ay);
        ax = fmaf(w1, f1.x, ax); ay = fmaf(w1, f1.y, ay);
    }
    if (e < e1) {
        uint2 p0 = csr[e];
        float w0 = __builtin_bit_cast(float, p0.y);
        float2 f0 = bf2f2(in[(size_t)p0.x * 64 + qd]);
        ax = fmaf(w0, f0.x, ax); ay = fmaf(w0, f0.y, ay);
    }
    ax += __shfl_xor(ax, 16, 64); ay += __shfl_xor(ay, 16, 64);
    ax += __shfl_xor(ax, 32, 64); ay += __shfl_xor(ay, 32, 64);

    if (lane < 16) {
        const size_t oq = (size_t)node * 64 + qd;
        if (MODE == 0) {
            outh[oq] = packbf(ax, ay);
        } else if (MODE == 1) {
            const int d0 = q * 32 + 2 * s, d1 = d0 + 1;
            float sc0 = bg[d0] * rsqrtf(bv[d0] + BN_EPS);
            float sh0 = (bb[d0] - bm[d0]) * sc0 + bbe[d0];
            float sc1 = bg[d1] * rsqrtf(bv[d1] + BN_EPS);
            float sh1 = (bb[d1] - bm[d1]) * sc1 + bbe[d1];
            outh[oq] = packbf(fmaxf(fmaf(ax, sc0, sh0), 0.f),
                              fmaxf(fmaf(ay, sc1, sh1), 0.f));
        } else if (MODE == 2) {
            float2 h2v = bf2f2(h2h[oq]);
            outh[oq] = packbf(fmaf(0.9f, ax, 0.1f * h2v.x),
                              fmaf(0.9f, ay, 0.1f * h2v.y));
        } else {
            float2 h2v = bf2f2(h2h[oq]);
            float2 z0v = bf2f2(z0h[oq]);
            float r0 = fmaf(0.9f, ax, 0.1f * h2v.x) + z0v.x;
            float r1 = fmaf(0.9f, ay, 0.1f * h2v.y) + z0v.y;
            *(float2*)&outf[(size_t)node * LAT + q * 32 + 2 * s] = make_float2(r0, r1);
            outh[oq] = packbf(r0, r1);
        }
    }
}

// ---------------- quartered edge dot: partial per quarter -------------------
__global__ __launch_bounds__(256) void edge_dot_q(const unsigned* __restrict__ zh,
                                                  const int* __restrict__ srcE,
                                                  const int* __restrict__ dstE,
                                                  float* __restrict__ partial, int E)
{
    const int b = blockIdx.x;
    const int q = (b & 7) >> 1;
    const int blk = ((b >> 3) << 1) | (b & 1);          // 0..49999
    const int wave = threadIdx.x >> 6;
    const int lane = threadIdx.x & 63;
    const int g = lane >> 4, s = lane & 15;
    const int e = blk * 16 + wave * 4 + g;
    const int r = srcE[e], c = dstE[e];
    float2 a = bf2f2(zh[(size_t)r * 64 + q * 16 + s]);
    float2 v = bf2f2(zh[(size_t)c * 64 + q * 16 + s]);
    float acc = a.x * v.x + a.y * v.y;
    acc += __shfl_xor(acc, 1, 64);
    acc += __shfl_xor(acc, 2, 64);
    acc += __shfl_xor(acc, 4, 64);
    acc += __shfl_xor(acc, 8, 64);
    if (s == 0) partial[(size_t)q * E + e] = acc;
}

__global__ void edge_combine_kernel(const float* __restrict__ partial,
                                    float* __restrict__ adj, int E)
{
    int e = blockIdx.x * 256 + threadIdx.x;
    if (e >= E) return;
    float d = partial[e] + partial[(size_t)E + e] + partial[2 * (size_t)E + e] + partial[3 * (size_t)E + e];
    adj[e] = 1.f / (1.f + expf(-d));
}

// ---------------- launcher ----------------
extern "C" void kernel_launch(void* const* d_in, const int* in_sizes, int n_in,
                              void* d_out, int out_size, void* d_ws, size_t ws_size,
                              hipStream_t stream)
{
    const float* x     = (const float*)d_in[0];
    const void*  ei    = d_in[1];
    const float* Wproj = (const float*)d_in[2];
    const float* W1    = (const float*)d_in[3];
    const float* b1    = (const float*)d_in[4];
    const float* g1    = (const float*)d_in[5];
    const float* be1   = (const float*)d_in[6];
    const float* m1    = (const float*)d_in[7];
    const float* v1    = (const float*)d_in[8];
    const float* W2    = (const float*)d_in[9];
    const float* b2    = (const float*)d_in[10];
    const float* g2    = (const float*)d_in[11];
    const float* be2   = (const float*)d_in[12];
    const float* m2    = (const float*)d_in[13];
    const float* v2    = (const float*)d_in[14];

    float* out_adj = (float*)d_out;
    float* out_z   = (float*)d_out + N_EDGES;

    char* w = (char*)d_ws;
    size_t off = 0;
    auto alloc = [&](size_t bytes) {
        void* p = w + off;
        off += (bytes + 255) & ~(size_t)255;
        return p;
    };
    const size_t NB = (size_t)N_NODES * 64 * 4;   // one bf16 [N,128] plane = 12.8 MB

    int*            flag   = (int*)           alloc(4);
    int*            cnt    = (int*)           alloc((size_t)N_NODES * 4);
    int*            cursor = (int*)           alloc((size_t)N_NODES * 4);
    int*            rowoff = (int*)           alloc((size_t)(N_NODES + 1) * 4);
    float*          dinv   = (float*)         alloc((size_t)N_NODES * 4);
    int*            srcE   = (int*)           alloc((size_t)N_EDGES * 4);
    int*            dstE   = (int*)           alloc((size_t)N_EDGES * 4);
    uint2*          csr    = (uint2*)         alloc((size_t)(N_EDGES + N_NODES) * 8);
    unsigned short* Wpt    = (unsigned short*)alloc((size_t)LAT * IN_DIM * 2);
    unsigned short* W1t    = (unsigned short*)alloc((size_t)HID * LAT * 2);
    unsigned short* W2t    = (unsigned short*)alloc((size_t)LAT * HID * 2);
    unsigned*       z0h    = (unsigned*)      alloc(NB);       // z0 bf16; final z mirror
    unsigned*       p0h    = (unsigned*)      alloc(NB);
    unsigned short* h1h    = (unsigned short*)alloc(2 * NB);   // [N,256]; later pingA/pingB
    unsigned*       t2h    = (unsigned*)      alloc(NB);       // later edge partials
    unsigned*       h2h    = (unsigned*)      alloc(NB);

    unsigned* pingA    = (unsigned*)h1h;
    unsigned* pingB    = (unsigned*)h1h + N_NODES * 64;
    float*    partials = (float*)t2h;

    // graph preprocessing
    detect_dtype_kernel<<<1, 256, 0, stream>>>((const int*)ei, flag);
    convert_edges_kernel<<<(N_EDGES + 255) / 256, 256, 0, stream>>>(ei, flag, srcE, dstE, N_EDGES);
    init_cnt_kernel<<<(N_NODES + 255) / 256, 256, 0, stream>>>(cnt, N_NODES);
    count_edges_kernel<<<(N_EDGES + 255) / 256, 256, 0, stream>>>(dstE, cnt, N_EDGES);
    scan_kernel<<<1, 1024, 0, stream>>>(cnt, rowoff, cursor, dinv, N_NODES);
    scatter_kernel<<<(N_EDGES + N_NODES + 255) / 256, 256, 0, stream>>>(srcE, dstE, dinv, cursor,
                                                                        csr, N_EDGES, N_NODES);

    // weight transposes (f32 -> bf16, [K][N] -> [N][K])
    transpose_cvt_kernel<<<(IN_DIM * LAT + 255) / 256, 256, 0, stream>>>(Wproj, Wpt, IN_DIM, LAT);
    transpose_cvt_kernel<<<(LAT * HID + 255) / 256, 256, 0, stream>>>(W1, W1t, LAT, HID);
    transpose_cvt_kernel<<<(HID * LAT + 255) / 256, 256, 0, stream>>>(W2, W2t, HID, LAT);

    const int gy = (N_NODES + 63) / 64;   // 782

    // z0h = bf16(x @ Wproj)
    gemm_mfma<IN_DIM, 0, true><<<dim3(1, gy), 256, 0, stream>>>(x, Wpt, (unsigned short*)z0h,
                                                                N_NODES, LAT,
                                                                nullptr, nullptr, nullptr, nullptr, nullptr);
    // p0h = bf16(prop(z0))        [ prop(z0 @ W1) == prop(z0) @ W1 ]
    prop_q<0><<<N_NODES, 256, 0, stream>>>(z0h, rowoff, csr, nullptr, nullptr, nullptr, p0h,
                                           nullptr, nullptr, nullptr, nullptr, nullptr);
    // h1h = bf16(relu(bn(p0 @ W1 + b1)))
    gemm_mfma<LAT, 1, false><<<dim3(2, gy), 256, 0, stream>>>(p0h, W1t, h1h, N_NODES, HID,
                                                              b1, g1, be1, m1, v1);
    // t2h = bf16(h1 @ W2)
    gemm_mfma<HID, 0, false><<<dim3(1, gy), 256, 0, stream>>>(h1h, W2t, (unsigned short*)t2h,
                                                              N_NODES, LAT,
                                                              nullptr, nullptr, nullptr, nullptr, nullptr);
    // h2h = bf16(relu(bn(prop(t2) + b2)))
    prop_q<1><<<N_NODES, 256, 0, stream>>>(t2h, rowoff, csr, nullptr, nullptr, nullptr, h2h,
                                           b2, g2, be2, m2, v2);

    // APPNP
    const unsigned* cur = h2h;
    for (int it = 0; it < K_ITERS; ++it) {
        if (it == K_ITERS - 1) {
            prop_q<3><<<N_NODES, 256, 0, stream>>>(cur, rowoff, csr, h2h, z0h, out_z, z0h,
                                                   nullptr, nullptr, nullptr, nullptr, nullptr);
        } else {
            unsigned* nxt = (it & 1) ? pingB : pingA;
            prop_q<2><<<N_NODES, 256, 0, stream>>>(cur, rowoff, csr, h2h, nullptr, nullptr, nxt,
                                                   nullptr, nullptr, nullptr, nullptr, nullptr);
            cur = nxt;
        }
    }

    // adj = sigmoid(z[row] . z[col]) via quartered partials
    edge_dot_q<<<4 * (N_EDGES / 16), 256, 0, stream>>>(z0h, srcE, dstE, partials, N_EDGES);
    edge_combine_kernel<<<(N_EDGES + 255) / 256, 256, 0, stream>>>(partials, out_adj, N_EDGES);
}

// Round 4
// 976.495 us; speedup vs baseline: 1.5785x; 1.5785x over previous
//
#include <hip/hip_runtime.h>

#define N_NODES 50000
#define N_EDGES 800000
#define IN_DIM  512
#define HID     256
#define LAT     128
#define K_ITERS 10
#define BN_EPS  1e-5f

typedef __attribute__((ext_vector_type(8))) short bf16x8;
typedef __attribute__((ext_vector_type(4))) float f32x4;

// ---------------- bf16 helpers ----------------
__device__ inline float2 bf2f2(unsigned v)
{
    float lo = __builtin_bit_cast(float, v << 16);
    float hi = __builtin_bit_cast(float, v & 0xffff0000u);
    return make_float2(lo, hi);
}
__device__ inline unsigned f2bf_bits(float f)
{
    unsigned u = __builtin_bit_cast(unsigned, f);
    return (u + 0x7fffu + ((u >> 16) & 1u)) >> 16;   // RTNE
}
__device__ inline unsigned packbf(float x, float y)
{
    return f2bf_bits(x) | (f2bf_bits(y) << 16);
}

// ---------------- edge dtype detect / normalize ----------------
__global__ void detect_dtype_kernel(const int* __restrict__ ei32, int* __restrict__ flag)
{
    __shared__ int any;
    if (threadIdx.x == 0) any = 0;
    __syncthreads();
    int local = 0;
    for (int i = threadIdx.x; i < 4096; i += blockDim.x)
        local |= ei32[2 * i + 1];
    if (local) atomicOr(&any, 1);
    __syncthreads();
    if (threadIdx.x == 0) flag[0] = (any != 0) ? 1 : 0;   // 1 => data is int32
}

__global__ void init_cnt_kernel(int* __restrict__ cnt, int n)
{
    int i = blockIdx.x * blockDim.x + threadIdx.x;
    if (i < n) cnt[i] = 1;   // self-loop
}

// fused convert + degree count
__global__ void convert_count_kernel(const void* __restrict__ ei, const int* __restrict__ flag,
                                     int* __restrict__ srcE, int* __restrict__ dstE,
                                     int* __restrict__ cnt, int E)
{
    int e = blockIdx.x * blockDim.x + threadIdx.x;
    if (e >= E) return;
    int s, d;
    if (*flag) {
        const int* p = (const int*)ei;
        s = p[e]; d = p[E + e];
    } else {
        const long long* p = (const long long*)ei;
        s = (int)p[e]; d = (int)p[E + e];
    }
    srcE[e] = s;
    dstE[e] = d;
    atomicAdd(&cnt[d], 1);
}

// ---------------- parallel scan (3 small kernels) ----------------
__global__ __launch_bounds__(256) void block_sum_kernel(const int* __restrict__ cnt,
                                                        int* __restrict__ bsum, int n)
{
    __shared__ int s[256];
    int i = blockIdx.x * 256 + threadIdx.x;
    s[threadIdx.x] = (i < n) ? cnt[i] : 0;
    __syncthreads();
    for (int off = 128; off > 0; off >>= 1) {
        if (threadIdx.x < off) s[threadIdx.x] += s[threadIdx.x + off];
        __syncthreads();
    }
    if (threadIdx.x == 0) bsum[blockIdx.x] = s[0];
}

__global__ __launch_bounds__(256) void block_scan_kernel(int* __restrict__ bsum, int nb)
{
    __shared__ int s[256];
    int t = threadIdx.x;
    int v = (t < nb) ? bsum[t] : 0;
    s[t] = v;
    __syncthreads();
    for (int off = 1; off < 256; off <<= 1) {
        int u = (t >= off) ? s[t - off] : 0;
        __syncthreads();
        s[t] += u;
        __syncthreads();
    }
    if (t < nb) bsum[t] = s[t] - v;   // exclusive block offsets
}

__global__ __launch_bounds__(256) void final_scan_kernel(const int* __restrict__ cnt,
                                                         const int* __restrict__ bsum,
                                                         int* __restrict__ rowoff,
                                                         int* __restrict__ cursor,
                                                         float* __restrict__ dinv, int n)
{
    __shared__ int s[256];
    int t = threadIdx.x;
    int i = blockIdx.x * 256 + t;
    int c = (i < n) ? cnt[i] : 0;
    s[t] = c;
    __syncthreads();
    for (int off = 1; off < 256; off <<= 1) {
        int u = (t >= off) ? s[t - off] : 0;
        __syncthreads();
        s[t] += u;
        __syncthreads();
    }
    if (i < n) {
        int excl = bsum[blockIdx.x] + s[t] - c;
        rowoff[i] = excl;
        cursor[i] = excl;
        dinv[i] = rsqrtf((float)c);
    }
    if (i == 0) rowoff[n] = N_EDGES + N_NODES;   // total is a constant
}

__global__ void scatter_kernel(const int* __restrict__ srcE, const int* __restrict__ dstE,
                               const float* __restrict__ dinv, int* __restrict__ cursor,
                               uint2* __restrict__ csr, int E, int n)
{
    int e = blockIdx.x * blockDim.x + threadIdx.x;
    if (e >= E + n) return;
    int s, d;
    if (e < E) { s = srcE[e]; d = dstE[e]; }
    else       { s = e - E;   d = s; }
    int pos = atomicAdd(&cursor[d], 1);
    float w = dinv[s] * dinv[d];
    csr[pos] = make_uint2((unsigned)s, __builtin_bit_cast(unsigned, w));
}

// ---------------- transpose-convert: in[R][C] f32 -> out[C][R] bf16 ----------
__global__ void transpose_cvt_kernel(const float* __restrict__ in, unsigned short* __restrict__ out,
                                     int R, int C)
{
    int idx = blockIdx.x * 256 + threadIdx.x;
    if (idx >= R * C) return;
    int c = idx / R, r = idx - c * R;
    out[idx] = (unsigned short)f2bf_bits(in[r * C + c]);
}

// ---------------- MFMA bf16 GEMM, no-LDS, B transposed [Nc][K] --------------
template<int KDIM, int EPI, bool AF32>
__global__ __launch_bounds__(256) void gemm_mfma(const void* __restrict__ Ain,
                                                 const unsigned short* __restrict__ Bt,
                                                 unsigned short* __restrict__ Cout,
                                                 int M, int Nc,
                                                 const float* __restrict__ cb,
                                                 const float* __restrict__ cg,
                                                 const float* __restrict__ cbe,
                                                 const float* __restrict__ cm,
                                                 const float* __restrict__ cv)
{
    const int wave = threadIdx.x >> 6;
    const int lane = threadIdx.x & 63;
    const int s  = lane & 15;
    const int kc = lane >> 4;
    const int wrow0   = blockIdx.y * 64 + wave * 16;
    const int colbase = blockIdx.x * 128;

    f32x4 acc[8] = {};

    const int arow = wrow0 + s;
    const bool aok = arow < M;

#pragma unroll 2
    for (int k0 = 0; k0 < KDIM; k0 += 32) {
        bf16x8 af = {};
        if (AF32) {
            if (aok) {
                const float* Ar = (const float*)Ain + (size_t)arow * KDIM + k0 + 8 * kc;
                float4 u0 = *(const float4*)Ar;
                float4 u1 = *(const float4*)(Ar + 4);
                af[0] = (short)f2bf_bits(u0.x); af[1] = (short)f2bf_bits(u0.y);
                af[2] = (short)f2bf_bits(u0.z); af[3] = (short)f2bf_bits(u0.w);
                af[4] = (short)f2bf_bits(u1.x); af[5] = (short)f2bf_bits(u1.y);
                af[6] = (short)f2bf_bits(u1.z); af[7] = (short)f2bf_bits(u1.w);
            }
        } else {
            if (aok)
                af = *(const bf16x8*)&((const unsigned short*)Ain)[(size_t)arow * KDIM + k0 + 8 * kc];
        }
#pragma unroll
        for (int t = 0; t < 8; ++t) {
            const int bn = colbase + t * 16 + s;
            bf16x8 bf = *(const bf16x8*)&Bt[(size_t)bn * KDIM + k0 + 8 * kc];
            acc[t] = __builtin_amdgcn_mfma_f32_16x16x32_bf16(af, bf, acc[t], 0, 0, 0);
        }
    }

#pragma unroll
    for (int t = 0; t < 8; ++t) {
        const int col = colbase + t * 16 + s;
        float sc = 1.f, sh = 0.f;
        if (EPI == 1) {
            sc = cg[col] * rsqrtf(cv[col] + BN_EPS);
            sh = (cb[col] - cm[col]) * sc + cbe[col];
        }
#pragma unroll
        for (int j = 0; j < 4; ++j) {
            const int crow = wrow0 + kc * 4 + j;
            if (crow < M) {
                float xv = acc[t][j];
                if (EPI == 1) xv = fmaxf(fmaf(xv, sc, sh), 0.f);
                Cout[(size_t)crow * Nc + col] = (unsigned short)f2bf_bits(xv);
            }
        }
    }
}

// ---------------- full-row propagate, 1 wave/node, 4-way unrolled -----------
// lane l holds dims (2l, 2l+1). csr loaded non-temporally (don't evict plane).
// MODE 0: out bf16. MODE 1: bn+relu -> bf16. MODE 2: 0.9a+0.1h2 -> bf16.
// MODE 3: final: f32 z to outf, bf16 mirror to outh (aliases z0h).
template<int MODE>
__global__ __launch_bounds__(256) void prop_row(const unsigned* __restrict__ in,
                                                const int* __restrict__ rowoff,
                                                const unsigned long long* __restrict__ csr,
                                                const unsigned* __restrict__ h2h,
                                                const unsigned* __restrict__ z0h,
                                                float* __restrict__ outf,
                                                unsigned* __restrict__ outh,
                                                const float* __restrict__ bb,
                                                const float* __restrict__ bg,
                                                const float* __restrict__ bbe,
                                                const float* __restrict__ bm,
                                                const float* __restrict__ bv)
{
    const int node = blockIdx.x * 4 + (threadIdx.x >> 6);
    const int lane = threadIdx.x & 63;
    const int e0 = rowoff[node], e1 = rowoff[node + 1];

    float2 A0 = {0.f, 0.f}, A1 = {0.f, 0.f}, A2 = {0.f, 0.f}, A3 = {0.f, 0.f};
    int e = e0;
    for (; e + 4 <= e1; e += 4) {
        unsigned long long p0 = __builtin_nontemporal_load(&csr[e]);
        unsigned long long p1 = __builtin_nontemporal_load(&csr[e + 1]);
        unsigned long long p2 = __builtin_nontemporal_load(&csr[e + 2]);
        unsigned long long p3 = __builtin_nontemporal_load(&csr[e + 3]);
        unsigned v0 = in[(size_t)(unsigned)p0 * 64 + lane];
        unsigned v1 = in[(size_t)(unsigned)p1 * 64 + lane];
        unsigned v2 = in[(size_t)(unsigned)p2 * 64 + lane];
        unsigned v3 = in[(size_t)(unsigned)p3 * 64 + lane];
        float w0 = __builtin_bit_cast(float, (unsigned)(p0 >> 32));
        float w1 = __builtin_bit_cast(float, (unsigned)(p1 >> 32));
        float w2 = __builtin_bit_cast(float, (unsigned)(p2 >> 32));
        float w3 = __builtin_bit_cast(float, (unsigned)(p3 >> 32));
        float2 f0 = bf2f2(v0), f1 = bf2f2(v1), f2 = bf2f2(v2), f3 = bf2f2(v3);
        A0.x = fmaf(w0, f0.x, A0.x); A0.y = fmaf(w0, f0.y, A0.y);
        A1.x = fmaf(w1, f1.x, A1.x); A1.y = fmaf(w1, f1.y, A1.y);
        A2.x = fmaf(w2, f2.x, A2.x); A2.y = fmaf(w2, f2.y, A2.y);
        A3.x = fmaf(w3, f3.x, A3.x); A3.y = fmaf(w3, f3.y, A3.y);
    }
    for (; e < e1; ++e) {
        unsigned long long p0 = __builtin_nontemporal_load(&csr[e]);
        float w0 = __builtin_bit_cast(float, (unsigned)(p0 >> 32));
        float2 f0 = bf2f2(in[(size_t)(unsigned)p0 * 64 + lane]);
        A0.x = fmaf(w0, f0.x, A0.x); A0.y = fmaf(w0, f0.y, A0.y);
    }
    float ax = (A0.x + A1.x) + (A2.x + A3.x);
    float ay = (A0.y + A1.y) + (A2.y + A3.y);

    const size_t o = (size_t)node * 64 + lane;
    if (MODE == 0) {
        outh[o] = packbf(ax, ay);
    } else if (MODE == 1) {
        const int d0 = 2 * lane, d1 = d0 + 1;
        float sc0 = bg[d0] * rsqrtf(bv[d0] + BN_EPS);
        float sh0 = (bb[d0] - bm[d0]) * sc0 + bbe[d0];
        float sc1 = bg[d1] * rsqrtf(bv[d1] + BN_EPS);
        float sh1 = (bb[d1] - bm[d1]) * sc1 + bbe[d1];
        outh[o] = packbf(fmaxf(fmaf(ax, sc0, sh0), 0.f),
                         fmaxf(fmaf(ay, sc1, sh1), 0.f));
    } else if (MODE == 2) {
        float2 h2v = bf2f2(h2h[o]);
        outh[o] = packbf(fmaf(0.9f, ax, 0.1f * h2v.x),
                         fmaf(0.9f, ay, 0.1f * h2v.y));
    } else {
        float2 h2v = bf2f2(h2h[o]);
        float2 z0v = bf2f2(z0h[o]);
        float r0 = fmaf(0.9f, ax, 0.1f * h2v.x) + z0v.x;
        float r1 = fmaf(0.9f, ay, 0.1f * h2v.y) + z0v.y;
        *(float2*)&outf[(size_t)node * LAT + 2 * lane] = make_float2(r0, r1);
        outh[o] = packbf(r0, r1);
    }
}

// ---------------- edge sigmoid-dot on bf16 z: one wave per edge --------------
__global__ __launch_bounds__(256) void edge_dot_bf16(const unsigned* __restrict__ zh,
                                                     const int* __restrict__ srcE,
                                                     const int* __restrict__ dstE,
                                                     float* __restrict__ adj, int E)
{
    int gw   = (blockIdx.x * 256 + threadIdx.x) >> 6;
    int lane = threadIdx.x & 63;
    if (gw >= E) return;
    int r = srcE[gw], c = dstE[gw];
    float2 a = bf2f2(zh[(size_t)r * 64 + lane]);
    float2 b = bf2f2(zh[(size_t)c * 64 + lane]);
    float acc = a.x * b.x + a.y * b.y;
#pragma unroll
    for (int m = 32; m >= 1; m >>= 1) acc += __shfl_xor(acc, m, 64);
    if (lane == 0) adj[gw] = 1.f / (1.f + expf(-acc));
}

// ---------------- launcher ----------------
extern "C" void kernel_launch(void* const* d_in, const int* in_sizes, int n_in,
                              void* d_out, int out_size, void* d_ws, size_t ws_size,
                              hipStream_t stream)
{
    const float* x     = (const float*)d_in[0];
    const void*  ei    = d_in[1];
    const float* Wproj = (const float*)d_in[2];
    const float* W1    = (const float*)d_in[3];
    const float* b1    = (const float*)d_in[4];
    const float* g1    = (const float*)d_in[5];
    const float* be1   = (const float*)d_in[6];
    const float* m1    = (const float*)d_in[7];
    const float* v1    = (const float*)d_in[8];
    const float* W2    = (const float*)d_in[9];
    const float* b2    = (const float*)d_in[10];
    const float* g2    = (const float*)d_in[11];
    const float* be2   = (const float*)d_in[12];
    const float* m2    = (const float*)d_in[13];
    const float* v2    = (const float*)d_in[14];

    float* out_adj = (float*)d_out;
    float* out_z   = (float*)d_out + N_EDGES;

    char* w = (char*)d_ws;
    size_t off = 0;
    auto alloc = [&](size_t bytes) {
        void* p = w + off;
        off += (bytes + 255) & ~(size_t)255;
        return p;
    };
    const size_t NB = (size_t)N_NODES * 64 * 4;   // one bf16 [N,128] plane = 12.8 MB
    const int NBLK = (N_NODES + 255) / 256;       // 196

    int*            flag   = (int*)           alloc(4);
    int*            cnt    = (int*)           alloc((size_t)N_NODES * 4);
    int*            cursor = (int*)           alloc((size_t)N_NODES * 4);
    int*            rowoff = (int*)           alloc((size_t)(N_NODES + 1) * 4);
    float*          dinv   = (float*)         alloc((size_t)N_NODES * 4);
    int*            bsum   = (int*)           alloc(256 * 4);
    int*            srcE   = (int*)           alloc((size_t)N_EDGES * 4);
    int*            dstE   = (int*)           alloc((size_t)N_EDGES * 4);
    uint2*          csr    = (uint2*)         alloc((size_t)(N_EDGES + N_NODES) * 8);
    unsigned short* Wpt    = (unsigned short*)alloc((size_t)LAT * IN_DIM * 2);
    unsigned short* W1t    = (unsigned short*)alloc((size_t)HID * LAT * 2);
    unsigned short* W2t    = (unsigned short*)alloc((size_t)LAT * HID * 2);
    unsigned*       z0h    = (unsigned*)      alloc(NB);       // z0 bf16; final z mirror
    unsigned*       p0h    = (unsigned*)      alloc(NB);
    unsigned short* h1h    = (unsigned short*)alloc(2 * NB);   // [N,256]; later pingA/pingB
    unsigned*       t2h    = (unsigned*)      alloc(NB);
    unsigned*       h2h    = (unsigned*)      alloc(NB);

    unsigned* pingA = (unsigned*)h1h;
    unsigned* pingB = (unsigned*)h1h + N_NODES * 64;

    // graph preprocessing
    detect_dtype_kernel<<<1, 256, 0, stream>>>((const int*)ei, flag);
    init_cnt_kernel<<<(N_NODES + 255) / 256, 256, 0, stream>>>(cnt, N_NODES);
    convert_count_kernel<<<(N_EDGES + 255) / 256, 256, 0, stream>>>(ei, flag, srcE, dstE, cnt, N_EDGES);
    block_sum_kernel<<<NBLK, 256, 0, stream>>>(cnt, bsum, N_NODES);
    block_scan_kernel<<<1, 256, 0, stream>>>(bsum, NBLK);
    final_scan_kernel<<<NBLK, 256, 0, stream>>>(cnt, bsum, rowoff, cursor, dinv, N_NODES);
    scatter_kernel<<<(N_EDGES + N_NODES + 255) / 256, 256, 0, stream>>>(srcE, dstE, dinv, cursor,
                                                                        csr, N_EDGES, N_NODES);

    // weight transposes (f32 -> bf16, [K][N] -> [N][K])
    transpose_cvt_kernel<<<(IN_DIM * LAT + 255) / 256, 256, 0, stream>>>(Wproj, Wpt, IN_DIM, LAT);
    transpose_cvt_kernel<<<(LAT * HID + 255) / 256, 256, 0, stream>>>(W1, W1t, LAT, HID);
    transpose_cvt_kernel<<<(HID * LAT + 255) / 256, 256, 0, stream>>>(W2, W2t, HID, LAT);

    const int gy = (N_NODES + 63) / 64;   // 782
    const int pgrid = N_NODES / 4;        // 12500

    // z0h = bf16(x @ Wproj)
    gemm_mfma<IN_DIM, 0, true><<<dim3(1, gy), 256, 0, stream>>>(x, Wpt, (unsigned short*)z0h,
                                                                N_NODES, LAT,
                                                                nullptr, nullptr, nullptr, nullptr, nullptr);
    // p0h = bf16(prop(z0))        [ prop(z0 @ W1) == prop(z0) @ W1 ]
    prop_row<0><<<pgrid, 256, 0, stream>>>(z0h, rowoff, (const unsigned long long*)csr,
                                           nullptr, nullptr, nullptr, p0h,
                                           nullptr, nullptr, nullptr, nullptr, nullptr);
    // h1h = bf16(relu(bn(p0 @ W1 + b1)))
    gemm_mfma<LAT, 1, false><<<dim3(2, gy), 256, 0, stream>>>(p0h, W1t, h1h, N_NODES, HID,
                                                              b1, g1, be1, m1, v1);
    // t2h = bf16(h1 @ W2)
    gemm_mfma<HID, 0, false><<<dim3(1, gy), 256, 0, stream>>>(h1h, W2t, (unsigned short*)t2h,
                                                              N_NODES, LAT,
                                                              nullptr, nullptr, nullptr, nullptr, nullptr);
    // h2h = bf16(relu(bn(prop(t2) + b2)))
    prop_row<1><<<pgrid, 256, 0, stream>>>(t2h, rowoff, (const unsigned long long*)csr,
                                           nullptr, nullptr, nullptr, h2h,
                                           b2, g2, be2, m2, v2);

    // APPNP
    const unsigned* cur = h2h;
    for (int it = 0; it < K_ITERS; ++it) {
        if (it == K_ITERS - 1) {
            prop_row<3><<<pgrid, 256, 0, stream>>>(cur, rowoff, (const unsigned long long*)csr,
                                                   h2h, z0h, out_z, z0h,
                                                   nullptr, nullptr, nullptr, nullptr, nullptr);
        } else {
            unsigned* nxt = (it & 1) ? pingB : pingA;
            prop_row<2><<<pgrid, 256, 0, stream>>>(cur, rowoff, (const unsigned long long*)csr,
                                                   h2h, nullptr, nullptr, nxt,
                                                   nullptr, nullptr, nullptr, nullptr, nullptr);
            cur = nxt;
        }
    }

    // adj = sigmoid(z[row] . z[col]) on bf16 mirror (now in z0h)
    edge_dot_bf16<<<(N_EDGES + 3) / 4, 256, 0, stream>>>(z0h, srcE, dstE, out_adj, N_EDGES);
}

// Round 5
// 746.781 us; speedup vs baseline: 2.0641x; 1.3076x over previous
//
#include <hip/hip_runtime.h>

#define N_NODES 50000
#define N_EDGES 800000
#define IN_DIM  512
#define HID     256
#define LAT     128
#define K_ITERS 10
#define BN_EPS  1e-5f

typedef __attribute__((ext_vector_type(8))) short bf16x8;
typedef __attribute__((ext_vector_type(4))) float f32x4;

// ---------------- bf16 helpers ----------------
__device__ inline float bflo(unsigned v) { return __builtin_bit_cast(float, v << 16); }
__device__ inline float bfhi(unsigned v) { return __builtin_bit_cast(float, v & 0xffff0000u); }
__device__ inline unsigned f2bf_bits(float f)
{
    unsigned u = __builtin_bit_cast(unsigned, f);
    return (u + 0x7fffu + ((u >> 16) & 1u)) >> 16;   // RTNE
}
__device__ inline unsigned packbf(float x, float y)
{
    return f2bf_bits(x) | (f2bf_bits(y) << 16);
}

// ---------------- edge dtype detect / normalize ----------------
__global__ void detect_dtype_kernel(const int* __restrict__ ei32, int* __restrict__ flag)
{
    __shared__ int any;
    if (threadIdx.x == 0) any = 0;
    __syncthreads();
    int local = 0;
    for (int i = threadIdx.x; i < 4096; i += blockDim.x)
        local |= ei32[2 * i + 1];
    if (local) atomicOr(&any, 1);
    __syncthreads();
    if (threadIdx.x == 0) flag[0] = (any != 0) ? 1 : 0;   // 1 => data is int32
}

__global__ void init_cnt_kernel(int* __restrict__ cnt, int n)
{
    int i = blockIdx.x * blockDim.x + threadIdx.x;
    if (i < n) cnt[i] = 1;   // self-loop
}

// fused convert + degree count
__global__ void convert_count_kernel(const void* __restrict__ ei, const int* __restrict__ flag,
                                     int* __restrict__ srcE, int* __restrict__ dstE,
                                     int* __restrict__ cnt, int E)
{
    int e = blockIdx.x * blockDim.x + threadIdx.x;
    if (e >= E) return;
    int s, d;
    if (*flag) {
        const int* p = (const int*)ei;
        s = p[e]; d = p[E + e];
    } else {
        const long long* p = (const long long*)ei;
        s = (int)p[e]; d = (int)p[E + e];
    }
    srcE[e] = s;
    dstE[e] = d;
    atomicAdd(&cnt[d], 1);
}

// ---------------- parallel scan (3 small kernels) ----------------
__global__ __launch_bounds__(256) void block_sum_kernel(const int* __restrict__ cnt,
                                                        int* __restrict__ bsum, int n)
{
    __shared__ int s[256];
    int i = blockIdx.x * 256 + threadIdx.x;
    s[threadIdx.x] = (i < n) ? cnt[i] : 0;
    __syncthreads();
    for (int off = 128; off > 0; off >>= 1) {
        if (threadIdx.x < off) s[threadIdx.x] += s[threadIdx.x + off];
        __syncthreads();
    }
    if (threadIdx.x == 0) bsum[blockIdx.x] = s[0];
}

__global__ __launch_bounds__(256) void block_scan_kernel(int* __restrict__ bsum, int nb)
{
    __shared__ int s[256];
    int t = threadIdx.x;
    int v = (t < nb) ? bsum[t] : 0;
    s[t] = v;
    __syncthreads();
    for (int off = 1; off < 256; off <<= 1) {
        int u = (t >= off) ? s[t - off] : 0;
        __syncthreads();
        s[t] += u;
        __syncthreads();
    }
    if (t < nb) bsum[t] = s[t] - v;   // exclusive block offsets
}

__global__ __launch_bounds__(256) void final_scan_kernel(const int* __restrict__ cnt,
                                                         const int* __restrict__ bsum,
                                                         int* __restrict__ rowoff,
                                                         int* __restrict__ cursor,
                                                         float* __restrict__ dinv, int n)
{
    __shared__ int s[256];
    int t = threadIdx.x;
    int i = blockIdx.x * 256 + t;
    int c = (i < n) ? cnt[i] : 0;
    s[t] = c;
    __syncthreads();
    for (int off = 1; off < 256; off <<= 1) {
        int u = (t >= off) ? s[t - off] : 0;
        __syncthreads();
        s[t] += u;
        __syncthreads();
    }
    if (i < n) {
        int excl = bsum[blockIdx.x] + s[t] - c;
        rowoff[i] = excl;
        cursor[i] = excl;
        dinv[i] = rsqrtf((float)c);
    }
    if (i == 0) rowoff[n] = N_EDGES + N_NODES;   // total is a constant
}

__global__ void scatter_kernel(const int* __restrict__ srcE, const int* __restrict__ dstE,
                               const float* __restrict__ dinv, int* __restrict__ cursor,
                               uint2* __restrict__ csr, int E, int n)
{
    int e = blockIdx.x * blockDim.x + threadIdx.x;
    if (e >= E + n) return;
    int s, d;
    if (e < E) { s = srcE[e]; d = dstE[e]; }
    else       { s = e - E;   d = s; }
    int pos = atomicAdd(&cursor[d], 1);
    float w = dinv[s] * dinv[d];
    csr[pos] = make_uint2((unsigned)s, __builtin_bit_cast(unsigned, w));
}

// ---------------- transpose-convert: in[R][C] f32 -> out[C][R] bf16 ----------
__global__ void transpose_cvt_kernel(const float* __restrict__ in, unsigned short* __restrict__ out,
                                     int R, int C)
{
    int idx = blockIdx.x * 256 + threadIdx.x;
    if (idx >= R * C) return;
    int c = idx / R, r = idx - c * R;
    out[idx] = (unsigned short)f2bf_bits(in[r * C + c]);
}

// ---------------- MFMA bf16 GEMM, no-LDS, B transposed [Nc][K] --------------
template<int KDIM, int EPI, bool AF32>
__global__ __launch_bounds__(256) void gemm_mfma(const void* __restrict__ Ain,
                                                 const unsigned short* __restrict__ Bt,
                                                 unsigned short* __restrict__ Cout,
                                                 int M, int Nc,
                                                 const float* __restrict__ cb,
                                                 const float* __restrict__ cg,
                                                 const float* __restrict__ cbe,
                                                 const float* __restrict__ cm,
                                                 const float* __restrict__ cv)
{
    const int wave = threadIdx.x >> 6;
    const int lane = threadIdx.x & 63;
    const int s  = lane & 15;
    const int kc = lane >> 4;
    const int wrow0   = blockIdx.y * 64 + wave * 16;
    const int colbase = blockIdx.x * 128;

    f32x4 acc[8] = {};

    const int arow = wrow0 + s;
    const bool aok = arow < M;

#pragma unroll 2
    for (int k0 = 0; k0 < KDIM; k0 += 32) {
        bf16x8 af = {};
        if (AF32) {
            if (aok) {
                const float* Ar = (const float*)Ain + (size_t)arow * KDIM + k0 + 8 * kc;
                float4 u0 = *(const float4*)Ar;
                float4 u1 = *(const float4*)(Ar + 4);
                af[0] = (short)f2bf_bits(u0.x); af[1] = (short)f2bf_bits(u0.y);
                af[2] = (short)f2bf_bits(u0.z); af[3] = (short)f2bf_bits(u0.w);
                af[4] = (short)f2bf_bits(u1.x); af[5] = (short)f2bf_bits(u1.y);
                af[6] = (short)f2bf_bits(u1.z); af[7] = (short)f2bf_bits(u1.w);
            }
        } else {
            if (aok)
                af = *(const bf16x8*)&((const unsigned short*)Ain)[(size_t)arow * KDIM + k0 + 8 * kc];
        }
#pragma unroll
        for (int t = 0; t < 8; ++t) {
            const int bn = colbase + t * 16 + s;
            bf16x8 bf = *(const bf16x8*)&Bt[(size_t)bn * KDIM + k0 + 8 * kc];
            acc[t] = __builtin_amdgcn_mfma_f32_16x16x32_bf16(af, bf, acc[t], 0, 0, 0);
        }
    }

#pragma unroll
    for (int t = 0; t < 8; ++t) {
        const int col = colbase + t * 16 + s;
        float sc = 1.f, sh = 0.f;
        if (EPI == 1) {
            sc = cg[col] * rsqrtf(cv[col] + BN_EPS);
            sh = (cb[col] - cm[col]) * sc + cbe[col];
        }
#pragma unroll
        for (int j = 0; j < 4; ++j) {
            const int crow = wrow0 + kc * 4 + j;
            if (crow < M) {
                float xv = acc[t][j];
                if (EPI == 1) xv = fmaxf(fmaf(xv, sc, sh), 0.f);
                Cout[(size_t)crow * Nc + col] = (unsigned short)f2bf_bits(xv);
            }
        }
    }
}

// ---------------- full-row propagate, 1 wave/node, 4 edge-groups x 16 lanes --
// Group g = lane>>4 handles edges e0+g, e0+g+4, ...; lane covers dims 8s..8s+7
// as one uint4 (dwordx4) gather. Cross-group combine via 2 shuffle rounds.
// MODE 0: out bf16. MODE 1: bn+relu -> bf16. MODE 2: 0.9a+0.1h2 -> bf16.
// MODE 3: final: f32 z to outf, bf16 mirror to outh (aliases z0h).
template<int MODE>
__global__ __launch_bounds__(256) void prop_row(const unsigned* __restrict__ in,
                                                const int* __restrict__ rowoff,
                                                const unsigned long long* __restrict__ csr,
                                                const unsigned* __restrict__ h2h,
                                                const unsigned* __restrict__ z0h,
                                                float* __restrict__ outf,
                                                unsigned* __restrict__ outh,
                                                const float* __restrict__ bb,
                                                const float* __restrict__ bg,
                                                const float* __restrict__ bbe,
                                                const float* __restrict__ bm,
                                                const float* __restrict__ bv)
{
    const int node = blockIdx.x * 4 + (threadIdx.x >> 6);
    const int lane = threadIdx.x & 63;
    const int g = lane >> 4, s = lane & 15;
    const int e0 = rowoff[node], e1 = rowoff[node + 1];

    float f[8] = {};
    int e = e0 + g;
    for (; e + 4 < e1; e += 8) {
        unsigned long long p0 = __builtin_nontemporal_load(&csr[e]);
        unsigned long long p1 = __builtin_nontemporal_load(&csr[e + 4]);
        uint4 v0 = *(const uint4*)&in[(size_t)(unsigned)p0 * 64 + 4 * s];
        uint4 v1 = *(const uint4*)&in[(size_t)(unsigned)p1 * 64 + 4 * s];
        float w0 = __builtin_bit_cast(float, (unsigned)(p0 >> 32));
        float w1 = __builtin_bit_cast(float, (unsigned)(p1 >> 32));
        f[0] = fmaf(w0, bflo(v0.x), f[0]); f[1] = fmaf(w0, bfhi(v0.x), f[1]);
        f[2] = fmaf(w0, bflo(v0.y), f[2]); f[3] = fmaf(w0, bfhi(v0.y), f[3]);
        f[4] = fmaf(w0, bflo(v0.z), f[4]); f[5] = fmaf(w0, bfhi(v0.z), f[5]);
        f[6] = fmaf(w0, bflo(v0.w), f[6]); f[7] = fmaf(w0, bfhi(v0.w), f[7]);
        f[0] = fmaf(w1, bflo(v1.x), f[0]); f[1] = fmaf(w1, bfhi(v1.x), f[1]);
        f[2] = fmaf(w1, bflo(v1.y), f[2]); f[3] = fmaf(w1, bfhi(v1.y), f[3]);
        f[4] = fmaf(w1, bflo(v1.z), f[4]); f[5] = fmaf(w1, bfhi(v1.z), f[5]);
        f[6] = fmaf(w1, bflo(v1.w), f[6]); f[7] = fmaf(w1, bfhi(v1.w), f[7]);
    }
    if (e < e1) {
        unsigned long long p0 = __builtin_nontemporal_load(&csr[e]);
        uint4 v0 = *(const uint4*)&in[(size_t)(unsigned)p0 * 64 + 4 * s];
        float w0 = __builtin_bit_cast(float, (unsigned)(p0 >> 32));
        f[0] = fmaf(w0, bflo(v0.x), f[0]); f[1] = fmaf(w0, bfhi(v0.x), f[1]);
        f[2] = fmaf(w0, bflo(v0.y), f[2]); f[3] = fmaf(w0, bfhi(v0.y), f[3]);
        f[4] = fmaf(w0, bflo(v0.z), f[4]); f[5] = fmaf(w0, bfhi(v0.z), f[5]);
        f[6] = fmaf(w0, bflo(v0.w), f[6]); f[7] = fmaf(w0, bfhi(v0.w), f[7]);
    }
#pragma unroll
    for (int i = 0; i < 8; ++i) {
        f[i] += __shfl_xor(f[i], 16, 64);
        f[i] += __shfl_xor(f[i], 32, 64);
    }

    if (g == 0) {
        const size_t o = (size_t)node * 64 + 4 * s;
        uint4 ov;
        if (MODE == 0) {
            ov.x = packbf(f[0], f[1]); ov.y = packbf(f[2], f[3]);
            ov.z = packbf(f[4], f[5]); ov.w = packbf(f[6], f[7]);
            *(uint4*)&outh[o] = ov;
        } else if (MODE == 1) {
            float4 G0 = *(const float4*)&bg[8 * s],  G1 = *(const float4*)&bg[8 * s + 4];
            float4 V0 = *(const float4*)&bv[8 * s],  V1 = *(const float4*)&bv[8 * s + 4];
            float4 B0 = *(const float4*)&bb[8 * s],  B1 = *(const float4*)&bb[8 * s + 4];
            float4 M0 = *(const float4*)&bm[8 * s],  M1 = *(const float4*)&bm[8 * s + 4];
            float4 E0 = *(const float4*)&bbe[8 * s], E1 = *(const float4*)&bbe[8 * s + 4];
            float gg[8] = {G0.x, G0.y, G0.z, G0.w, G1.x, G1.y, G1.z, G1.w};
            float vv[8] = {V0.x, V0.y, V0.z, V0.w, V1.x, V1.y, V1.z, V1.w};
            float bbv[8] = {B0.x, B0.y, B0.z, B0.w, B1.x, B1.y, B1.z, B1.w};
            float mm[8] = {M0.x, M0.y, M0.z, M0.w, M1.x, M1.y, M1.z, M1.w};
            float ee[8] = {E0.x, E0.y, E0.z, E0.w, E1.x, E1.y, E1.z, E1.w};
            float r[8];
#pragma unroll
            for (int i = 0; i < 8; ++i) {
                float sc = gg[i] * rsqrtf(vv[i] + BN_EPS);
                float sh = (bbv[i] - mm[i]) * sc + ee[i];
                r[i] = fmaxf(fmaf(f[i], sc, sh), 0.f);
            }
            ov.x = packbf(r[0], r[1]); ov.y = packbf(r[2], r[3]);
            ov.z = packbf(r[4], r[5]); ov.w = packbf(r[6], r[7]);
            *(uint4*)&outh[o] = ov;
        } else if (MODE == 2) {
            uint4 hv = *(const uint4*)&h2h[o];
            ov.x = packbf(fmaf(0.9f, f[0], 0.1f * bflo(hv.x)), fmaf(0.9f, f[1], 0.1f * bfhi(hv.x)));
            ov.y = packbf(fmaf(0.9f, f[2], 0.1f * bflo(hv.y)), fmaf(0.9f, f[3], 0.1f * bfhi(hv.y)));
            ov.z = packbf(fmaf(0.9f, f[4], 0.1f * bflo(hv.z)), fmaf(0.9f, f[5], 0.1f * bfhi(hv.z)));
            ov.w = packbf(fmaf(0.9f, f[6], 0.1f * bflo(hv.w)), fmaf(0.9f, f[7], 0.1f * bfhi(hv.w)));
            *(uint4*)&outh[o] = ov;
        } else {
            uint4 hv = *(const uint4*)&h2h[o];
            uint4 zv = *(const uint4*)&z0h[o];
            float r[8];
            r[0] = fmaf(0.9f, f[0], 0.1f * bflo(hv.x)) + bflo(zv.x);
            r[1] = fmaf(0.9f, f[1], 0.1f * bfhi(hv.x)) + bfhi(zv.x);
            r[2] = fmaf(0.9f, f[2], 0.1f * bflo(hv.y)) + bflo(zv.y);
            r[3] = fmaf(0.9f, f[3], 0.1f * bfhi(hv.y)) + bfhi(zv.y);
            r[4] = fmaf(0.9f, f[4], 0.1f * bflo(hv.z)) + bflo(zv.z);
            r[5] = fmaf(0.9f, f[5], 0.1f * bfhi(hv.z)) + bfhi(zv.z);
            r[6] = fmaf(0.9f, f[6], 0.1f * bflo(hv.w)) + bflo(zv.w);
            r[7] = fmaf(0.9f, f[7], 0.1f * bfhi(hv.w)) + bfhi(zv.w);
            *(float4*)&outf[(size_t)node * LAT + 8 * s]     = make_float4(r[0], r[1], r[2], r[3]);
            *(float4*)&outf[(size_t)node * LAT + 8 * s + 4] = make_float4(r[4], r[5], r[6], r[7]);
            ov.x = packbf(r[0], r[1]); ov.y = packbf(r[2], r[3]);
            ov.z = packbf(r[4], r[5]); ov.w = packbf(r[6], r[7]);
            *(uint4*)&outh[o] = ov;
        }
    }
}

// ---------------- MFMA edge dot: 16 edges per wave ---------------------------
// A-frag = z[src[base+s]], B-frag = z[dst[base+s]]; diag of C = the 16 dots.
__global__ __launch_bounds__(256) void edge_dot_mfma(const unsigned* __restrict__ zh,
                                                     const int* __restrict__ srcE,
                                                     const int* __restrict__ dstE,
                                                     float* __restrict__ adj)
{
    const int gw = blockIdx.x * 4 + (threadIdx.x >> 6);
    const int base = gw * 16;
    const int lane = threadIdx.x & 63;
    const int s = lane & 15, kc = lane >> 4;
    const int r = srcE[base + s];
    const int c = dstE[base + s];
    const unsigned* zr = &zh[(size_t)r * 64 + 4 * kc];
    const unsigned* zc = &zh[(size_t)c * 64 + 4 * kc];
    f32x4 acc = {};
#pragma unroll
    for (int k0 = 0; k0 < 4; ++k0) {
        bf16x8 af = *(const bf16x8*)(zr + 16 * k0);
        bf16x8 bf = *(const bf16x8*)(zc + 16 * k0);
        acc = __builtin_amdgcn_mfma_f32_16x16x32_bf16(af, bf, acc, 0, 0, 0);
    }
    if ((s >> 2) == kc) {
        const int j = s & 3;
        float v = (j == 0) ? acc[0] : (j == 1) ? acc[1] : (j == 2) ? acc[2] : acc[3];
        adj[base + s] = 1.f / (1.f + expf(-v));
    }
}

// ---------------- launcher ----------------
extern "C" void kernel_launch(void* const* d_in, const int* in_sizes, int n_in,
                              void* d_out, int out_size, void* d_ws, size_t ws_size,
                              hipStream_t stream)
{
    const float* x     = (const float*)d_in[0];
    const void*  ei    = d_in[1];
    const float* Wproj = (const float*)d_in[2];
    const float* W1    = (const float*)d_in[3];
    const float* b1    = (const float*)d_in[4];
    const float* g1    = (const float*)d_in[5];
    const float* be1   = (const float*)d_in[6];
    const float* m1    = (const float*)d_in[7];
    const float* v1    = (const float*)d_in[8];
    const float* W2    = (const float*)d_in[9];
    const float* b2    = (const float*)d_in[10];
    const float* g2    = (const float*)d_in[11];
    const float* be2   = (const float*)d_in[12];
    const float* m2    = (const float*)d_in[13];
    const float* v2    = (const float*)d_in[14];

    float* out_adj = (float*)d_out;
    float* out_z   = (float*)d_out + N_EDGES;

    char* w = (char*)d_ws;
    size_t off = 0;
    auto alloc = [&](size_t bytes) {
        void* p = w + off;
        off += (bytes + 255) & ~(size_t)255;
        return p;
    };
    const size_t NB = (size_t)N_NODES * 64 * 4;   // one bf16 [N,128] plane = 12.8 MB
    const int NBLK = (N_NODES + 255) / 256;       // 196

    int*            flag   = (int*)           alloc(4);
    int*            cnt    = (int*)           alloc((size_t)N_NODES * 4);
    int*            cursor = (int*)           alloc((size_t)N_NODES * 4);
    int*            rowoff = (int*)           alloc((size_t)(N_NODES + 1) * 4);
    float*          dinv   = (float*)         alloc((size_t)N_NODES * 4);
    int*            bsum   = (int*)           alloc(256 * 4);
    int*            srcE   = (int*)           alloc((size_t)N_EDGES * 4);
    int*            dstE   = (int*)           alloc((size_t)N_EDGES * 4);
    uint2*          csr    = (uint2*)         alloc((size_t)(N_EDGES + N_NODES) * 8);
    unsigned short* Wpt    = (unsigned short*)alloc((size_t)LAT * IN_DIM * 2);
    unsigned short* W1t    = (unsigned short*)alloc((size_t)HID * LAT * 2);
    unsigned short* W2t    = (unsigned short*)alloc((size_t)LAT * HID * 2);
    unsigned*       z0h    = (unsigned*)      alloc(NB);       // z0 bf16; final z mirror
    unsigned*       p0h    = (unsigned*)      alloc(NB);
    unsigned short* h1h    = (unsigned short*)alloc(2 * NB);   // [N,256]; later pingA/pingB
    unsigned*       t2h    = (unsigned*)      alloc(NB);
    unsigned*       h2h    = (unsigned*)      alloc(NB);

    unsigned* pingA = (unsigned*)h1h;
    unsigned* pingB = (unsigned*)h1h + N_NODES * 64;

    // graph preprocessing
    detect_dtype_kernel<<<1, 256, 0, stream>>>((const int*)ei, flag);
    init_cnt_kernel<<<(N_NODES + 255) / 256, 256, 0, stream>>>(cnt, N_NODES);
    convert_count_kernel<<<(N_EDGES + 255) / 256, 256, 0, stream>>>(ei, flag, srcE, dstE, cnt, N_EDGES);
    block_sum_kernel<<<NBLK, 256, 0, stream>>>(cnt, bsum, N_NODES);
    block_scan_kernel<<<1, 256, 0, stream>>>(bsum, NBLK);
    final_scan_kernel<<<NBLK, 256, 0, stream>>>(cnt, bsum, rowoff, cursor, dinv, N_NODES);
    scatter_kernel<<<(N_EDGES + N_NODES + 255) / 256, 256, 0, stream>>>(srcE, dstE, dinv, cursor,
                                                                        csr, N_EDGES, N_NODES);

    // weight transposes (f32 -> bf16, [K][N] -> [N][K])
    transpose_cvt_kernel<<<(IN_DIM * LAT + 255) / 256, 256, 0, stream>>>(Wproj, Wpt, IN_DIM, LAT);
    transpose_cvt_kernel<<<(LAT * HID + 255) / 256, 256, 0, stream>>>(W1, W1t, LAT, HID);
    transpose_cvt_kernel<<<(HID * LAT + 255) / 256, 256, 0, stream>>>(W2, W2t, HID, LAT);

    const int gy = (N_NODES + 63) / 64;   // 782
    const int pgrid = N_NODES / 4;        // 12500

    // z0h = bf16(x @ Wproj)
    gemm_mfma<IN_DIM, 0, true><<<dim3(1, gy), 256, 0, stream>>>(x, Wpt, (unsigned short*)z0h,
                                                                N_NODES, LAT,
                                                                nullptr, nullptr, nullptr, nullptr, nullptr);
    // p0h = bf16(prop(z0))        [ prop(z0 @ W1) == prop(z0) @ W1 ]
    prop_row<0><<<pgrid, 256, 0, stream>>>(z0h, rowoff, (const unsigned long long*)csr,
                                           nullptr, nullptr, nullptr, p0h,
                                           nullptr, nullptr, nullptr, nullptr, nullptr);
    // h1h = bf16(relu(bn(p0 @ W1 + b1)))
    gemm_mfma<LAT, 1, false><<<dim3(2, gy), 256, 0, stream>>>(p0h, W1t, h1h, N_NODES, HID,
                                                              b1, g1, be1, m1, v1);
    // t2h = bf16(h1 @ W2)
    gemm_mfma<HID, 0, false><<<dim3(1, gy), 256, 0, stream>>>(h1h, W2t, (unsigned short*)t2h,
                                                              N_NODES, LAT,
                                                              nullptr, nullptr, nullptr, nullptr, nullptr);
    // h2h = bf16(relu(bn(prop(t2) + b2)))
    prop_row<1><<<pgrid, 256, 0, stream>>>(t2h, rowoff, (const unsigned long long*)csr,
                                           nullptr, nullptr, nullptr, h2h,
                                           b2, g2, be2, m2, v2);

    // APPNP
    const unsigned* cur = h2h;
    for (int it = 0; it < K_ITERS; ++it) {
        if (it == K_ITERS - 1) {
            prop_row<3><<<pgrid, 256, 0, stream>>>(cur, rowoff, (const unsigned long long*)csr,
                                                   h2h, z0h, out_z, z0h,
                                                   nullptr, nullptr, nullptr, nullptr, nullptr);
        } else {
            unsigned* nxt = (it & 1) ? pingB : pingA;
            prop_row<2><<<pgrid, 256, 0, stream>>>(cur, rowoff, (const unsigned long long*)csr,
                                                   h2h, nullptr, nullptr, nxt,
                                                   nullptr, nullptr, nullptr, nullptr, nullptr);
            cur = nxt;
        }
    }

    // adj = sigmoid(z[row] . z[col]) on bf16 mirror (now in z0h), 16 edges/wave
    edge_dot_mfma<<<N_EDGES / 64, 256, 0, stream>>>(z0h, srcE, dstE, out_adj);
}